// Round 6
// baseline (408.772 us; speedup 1.0000x reference)
//
#include <hip/hip_runtime.h>

// ---------------- workspace layout (floats) ----------------
#define N_P1    (512*16*50*32)          // 13,107,200
#define N_FEAT  (512*12800)             // 6,553,600
#define N_PART  (32*512*256)            // 4,194,304

#define WS_P1    0
#define WS_FEAT  (WS_P1 + N_P1)
#define WS_PART  (WS_FEAT + N_FEAT)
// after conv2 consumes P1, its region is reused for the SNN tail:
#define WS_S1    0                       // 25*512*256 = 3,276,800  [t][b][k]
#define WS_IN2   3276800                 // 25*512*128 = 1,638,400
#define WS_S2    4915200                 // 25*512*128 = 1,638,400

// ---------------- conv1: mean over T + conv3x3 + bn-fold + relu + pool ----------------
__global__ __launch_bounds__(256) void conv1_kernel(const float* __restrict__ x,
                                                    const float* __restrict__ w1,
                                                    const float* __restrict__ cb1,
                                                    const float* __restrict__ g1,
                                                    const float* __restrict__ bb1,
                                                    const float* __restrict__ m1g,
                                                    const float* __restrict__ v1,
                                                    float* __restrict__ p1) {
    __shared__ float xs[22 * 66];
    __shared__ float w1s[144];
    __shared__ float sh1s[16];
    const int b = blockIdx.x, s = blockIdx.y;
    const int tid = threadIdx.x;
    if (tid < 144) {
        int c = tid / 9;
        float inv = g1[c] * rsqrtf(v1[c] + 1e-5f);
        w1s[tid] = w1[tid] * inv;
    }
    if (tid < 16) {
        float inv = g1[tid] * rsqrtf(v1[tid] + 1e-5f);
        sh1s[tid] = cb1[tid] * inv + bb1[tid] - m1g[tid] * inv;
    }
    if (tid < 44) xs[(tid >> 1) * 66 + (tid & 1) * 65] = 0.f;   // border cols
    const int r0 = s * 20 - 1;
    const size_t TSTR = (size_t)512 * 6400;
    for (int i = tid; i < 22 * 16; i += 256) {
        int lr = i >> 4, cq = i & 15;
        int gr = r0 + lr;
        float4 a0 = make_float4(0.f, 0.f, 0.f, 0.f), a1 = a0, a2 = a0, a3 = a0;
        if (gr >= 0 && gr < 100) {
            const float* px = x + (size_t)b * 6400 + gr * 64 + cq * 4;
            #pragma unroll
            for (int tt = 0; tt < 24; tt += 4) {
                float4 v0 = *(const float4*)(px + (size_t)(tt + 0) * TSTR);
                float4 v1_ = *(const float4*)(px + (size_t)(tt + 1) * TSTR);
                float4 v2_ = *(const float4*)(px + (size_t)(tt + 2) * TSTR);
                float4 v3 = *(const float4*)(px + (size_t)(tt + 3) * TSTR);
                a0.x += v0.x; a0.y += v0.y; a0.z += v0.z; a0.w += v0.w;
                a1.x += v1_.x; a1.y += v1_.y; a1.z += v1_.z; a1.w += v1_.w;
                a2.x += v2_.x; a2.y += v2_.y; a2.z += v2_.z; a2.w += v2_.w;
                a3.x += v3.x; a3.y += v3.y; a3.z += v3.z; a3.w += v3.w;
            }
            float4 v = *(const float4*)(px + (size_t)24 * TSTR);
            a0.x += v.x; a0.y += v.y; a0.z += v.z; a0.w += v.w;
        }
        const float sc = 1.0f / 25.0f;
        float* d = &xs[lr * 66 + 1 + cq * 4];
        d[0] = (a0.x + a1.x + a2.x + a3.x) * sc;
        d[1] = (a0.y + a1.y + a2.y + a3.y) * sc;
        d[2] = (a0.z + a1.z + a2.z + a3.z) * sc;
        d[3] = (a0.w + a1.w + a2.w + a3.w) * sc;
    }
    __syncthreads();
    for (int pos = tid; pos < 320; pos += 256) {
        int phl = pos >> 5, pw = pos & 31;
        int ph = s * 10 + phl;
        float win[4][4];
        #pragma unroll
        for (int a = 0; a < 4; ++a)
            #pragma unroll
            for (int c2 = 0; c2 < 4; ++c2)
                win[a][c2] = xs[(2 * phl + a) * 66 + 2 * pw + c2];
        #pragma unroll 1
        for (int c = 0; c < 16; ++c) {
            float s00 = 0.f, s01 = 0.f, s10 = 0.f, s11 = 0.f;
            #pragma unroll
            for (int dh = 0; dh < 3; ++dh)
                #pragma unroll
                for (int dw = 0; dw < 3; ++dw) {
                    float w = w1s[c * 9 + dh * 3 + dw];
                    s00 = fmaf(win[dh][dw],         w, s00);
                    s01 = fmaf(win[dh][dw + 1],     w, s01);
                    s10 = fmaf(win[dh + 1][dw],     w, s10);
                    s11 = fmaf(win[dh + 1][dw + 1], w, s11);
                }
            float m = fmaxf(fmaxf(s00, s01), fmaxf(s10, s11));
            float val = fmaxf(m + sh1s[c], 0.f);
            p1[(((size_t)b * 16 + c) * 50 + ph) * 32 + pw] = val;
        }
    }
}

// ---------------- conv2: conv3x3(16->32) + bn-fold + relu + pool, zero-waste ----------------
__global__ __launch_bounds__(320) void conv2_kernel(const float* __restrict__ p1,
                                                    const float* __restrict__ w2g,
                                                    const float* __restrict__ cb2,
                                                    const float* __restrict__ g2,
                                                    const float* __restrict__ bb2,
                                                    const float* __restrict__ m2g,
                                                    const float* __restrict__ v2,
                                                    float* __restrict__ feat) {
    __shared__ float ins[16 * 12 * 36];   // [ci][row -1..10][col -1..34]
    __shared__ float wl[16 * 9 * 32];     // [ci][tap][c]
    __shared__ float sh2s[32];
    const int b = blockIdx.x, s = blockIdx.y;
    const int tid = threadIdx.x;
    const int chg = tid & 15, q = (tid >> 4) & 3, phl = tid >> 6;
    const int ph = s * 5 + phl;

    for (int i = tid; i < 192; i += 320) {
        int ci = i / 12, lr = i - ci * 12;
        int gr = s * 10 - 1 + lr;
        float* dst = &ins[(ci * 12 + lr) * 36];
        if (gr >= 0 && gr < 50) {
            const float* src = p1 + (((size_t)b * 16 + ci) * 50 + gr) * 32;
            float4 v0 = *(const float4*)src;
            dst[0] = 0.f; dst[1] = v0.x; dst[2] = v0.y; dst[3] = v0.z;
            #pragma unroll
            for (int qq = 1; qq < 8; ++qq) {
                float4 v = *(const float4*)(src + 4 * qq - 1);
                *(float4*)(dst + 4 * qq) = v;
            }
            dst[32] = src[31];
            dst[33] = 0.f; dst[34] = 0.f; dst[35] = 0.f;
        } else {
            #pragma unroll
            for (int qq = 0; qq < 9; ++qq) *(float4*)(dst + 4 * qq) = make_float4(0.f, 0.f, 0.f, 0.f);
        }
    }
    for (int i = tid; i < 4608; i += 320) {
        int c = i / 144, rem = i - c * 144;
        float inv = g2[c] * rsqrtf(v2[c] + 1e-5f);
        wl[rem * 32 + c] = w2g[i] * inv;
    }
    if (tid < 32) {
        float inv = g2[tid] * rsqrtf(v2[tid] + 1e-5f);
        sh2s[tid] = cb2[tid] * inv + bb2[tid] - m2g[tid] * inv;
    }
    __syncthreads();

    float acc[2][2][8];
    #pragma unroll
    for (int c = 0; c < 2; ++c)
        #pragma unroll
        for (int a = 0; a < 2; ++a)
            #pragma unroll
            for (int xx = 0; xx < 8; ++xx) acc[c][a][xx] = 0.f;
    const int xb = q * 8;
    #pragma unroll 1
    for (int ci = 0; ci < 16; ++ci) {
        float2 wv[9];
        #pragma unroll
        for (int t = 0; t < 9; ++t)
            wv[t] = *(const float2*)&wl[(ci * 9 + t) * 32 + 2 * chg];
        #pragma unroll
        for (int lr4 = 0; lr4 < 4; ++lr4) {
            const float* row = &ins[(ci * 12 + (2 * phl + lr4)) * 36 + xb];
            float v[10];
            float4 t0 = *(const float4*)&row[0];
            float4 t1 = *(const float4*)&row[4];
            float2 t2 = *(const float2*)&row[8];
            v[0]=t0.x; v[1]=t0.y; v[2]=t0.z; v[3]=t0.w;
            v[4]=t1.x; v[5]=t1.y; v[6]=t1.z; v[7]=t1.w;
            v[8]=t2.x; v[9]=t2.y;
            #pragma unroll
            for (int a = 0; a < 2; ++a) {
                const int dh = lr4 - a;
                if (dh >= 0 && dh <= 2) {
                    #pragma unroll
                    for (int dw = 0; dw < 3; ++dw) {
                        float w0 = wv[dh * 3 + dw].x;
                        float w1 = wv[dh * 3 + dw].y;
                        #pragma unroll
                        for (int xx = 0; xx < 8; ++xx) {
                            acc[0][a][xx] = fmaf(v[xx + dw], w0, acc[0][a][xx]);
                            acc[1][a][xx] = fmaf(v[xx + dw], w1, acc[1][a][xx]);
                        }
                    }
                }
            }
        }
    }
    #pragma unroll
    for (int ch = 0; ch < 2; ++ch) {
        const int c = 2 * chg + ch;
        const float sh = sh2s[c];
        #pragma unroll
        for (int p = 0; p < 4; ++p) {
            float m = fmaxf(fmaxf(acc[ch][0][2 * p], acc[ch][0][2 * p + 1]),
                            fmaxf(acc[ch][1][2 * p], acc[ch][1][2 * p + 1]));
            float val = fmaxf(m + sh, 0.f);
            feat[(((size_t)b * 32 + c) * 25 + ph) * 16 + q * 4 + p] = val;
        }
    }
}

// ---------------- fc1: split-K f32 GEMM, 64x128 tile, 4x8 micro ----------------
__global__ __launch_bounds__(256) void fc1_kernel(const float* __restrict__ feat,
                                                  const float* __restrict__ w,
                                                  float* __restrict__ part) {
    __shared__ float As[16 * 68];
    __shared__ float Bs[16 * 136];
    const int bx = blockIdx.x, by = blockIdx.y, bz = blockIdx.z;
    const int tid = threadIdx.x;
    const int tm = tid >> 4, tn = tid & 15;
    const int r = tid >> 2, cq = tid & 3;
    const int m0 = bx * 64, n0 = by * 128;
    const size_t aBase = (size_t)(m0 + r) * 12800 + bz * 400 + cq * 4;
    const size_t bBase = (size_t)(n0 + r) * 12800 + bz * 400 + cq * 4;
    float acc[4][8];
    #pragma unroll
    for (int i = 0; i < 4; ++i)
        #pragma unroll
        for (int j = 0; j < 8; ++j) acc[i][j] = 0.f;

    for (int kt = 0; kt < 25; ++kt) {
        float4 a0 = *(const float4*)(feat + aBase + kt * 16);
        float4 b0 = *(const float4*)(w    + bBase + kt * 16);
        float4 b1 = *(const float4*)(w    + bBase + (size_t)64 * 12800 + kt * 16);
        __syncthreads();
        As[(cq * 4 + 0) * 68 + r] = a0.x; As[(cq * 4 + 1) * 68 + r] = a0.y;
        As[(cq * 4 + 2) * 68 + r] = a0.z; As[(cq * 4 + 3) * 68 + r] = a0.w;
        Bs[(cq * 4 + 0) * 136 + r]      = b0.x; Bs[(cq * 4 + 1) * 136 + r]      = b0.y;
        Bs[(cq * 4 + 2) * 136 + r]      = b0.z; Bs[(cq * 4 + 3) * 136 + r]      = b0.w;
        Bs[(cq * 4 + 0) * 136 + 64 + r] = b1.x; Bs[(cq * 4 + 1) * 136 + 64 + r] = b1.y;
        Bs[(cq * 4 + 2) * 136 + 64 + r] = b1.z; Bs[(cq * 4 + 3) * 136 + 64 + r] = b1.w;
        __syncthreads();
        #pragma unroll
        for (int kk = 0; kk < 16; ++kk) {
            float4 av  = *(const float4*)&As[kk * 68 + tm * 4];
            float4 bv0 = *(const float4*)&Bs[kk * 136 + tn * 8];
            float4 bv1 = *(const float4*)&Bs[kk * 136 + tn * 8 + 4];
            float a_[4] = {av.x, av.y, av.z, av.w};
            float b_[8] = {bv0.x, bv0.y, bv0.z, bv0.w, bv1.x, bv1.y, bv1.z, bv1.w};
            #pragma unroll
            for (int i = 0; i < 4; ++i)
                #pragma unroll
                for (int j = 0; j < 8; ++j)
                    acc[i][j] = fmaf(a_[i], b_[j], acc[i][j]);
        }
    }
    #pragma unroll
    for (int i = 0; i < 4; ++i) {
        float* dst = &part[(size_t)bz * 131072 + (size_t)(m0 + tm * 4 + i) * 256 + n0 + tn * 8];
        *(float4*)dst       = make_float4(acc[i][0], acc[i][1], acc[i][2], acc[i][3]);
        *(float4*)(dst + 4) = make_float4(acc[i][4], acc[i][5], acc[i][6], acc[i][7]);
    }
}

// ---------------- lif1: reduce fc1 partials + 25-step m1 scan -> S1 (t,b,k) ----------------
__global__ __launch_bounds__(256) void lif1_kernel(const float* __restrict__ part,
                                                   const float* __restrict__ b1g,
                                                   const float* __restrict__ pb1,
                                                   float* __restrict__ S1) {
    const int i = blockIdx.x * 256 + threadIdx.x;    // 131072 = 512 b x 256 k
    const int k = i & 255;
    float cu = b1g[k];
    #pragma unroll 8
    for (int z = 0; z < 32; ++z) cu += part[(size_t)z * 131072 + i];
    const float be = fminf(fmaxf(pb1[0], 0.f), 1.f);
    float m = 0.f;
    #pragma unroll
    for (int t = 0; t < 25; ++t) {
        float r = (m > 1.f) ? 1.f : 0.f;
        m = fmaf(be, m, cu) - r;
        S1[(size_t)t * 131072 + i] = (m > 1.f) ? 1.f : 0.f;
    }
}

// ---------------- fc2 GEMM: in2(12800,128) = S1(12800,256) @ w2^T + b2 ----------------
__global__ __launch_bounds__(256) void fc2g_kernel(const float* __restrict__ S1,
                                                   const float* __restrict__ w2g,
                                                   const float* __restrict__ b2g,
                                                   float* __restrict__ in2) {
    __shared__ float As[16 * 36];
    __shared__ float Bs[16 * 136];
    const int m0 = blockIdx.x * 32;
    const int tid = threadIdx.x;
    const int tm = tid >> 4, tn = tid & 15;
    float acc[2][8];
    #pragma unroll
    for (int i = 0; i < 2; ++i)
        #pragma unroll
        for (int j = 0; j < 8; ++j) acc[i][j] = 0.f;

    for (int kt = 0; kt < 16; ++kt) {
        float4 av = make_float4(0.f, 0.f, 0.f, 0.f);
        if (tid < 128) {
            int r = tid >> 2, cq = tid & 3;
            av = *(const float4*)&S1[(size_t)(m0 + r) * 256 + kt * 16 + cq * 4];
        }
        int rb = tid >> 1, kb = (tid & 1) * 8;
        float4 bv0 = *(const float4*)&w2g[rb * 256 + kt * 16 + kb];
        float4 bv1 = *(const float4*)&w2g[rb * 256 + kt * 16 + kb + 4];
        __syncthreads();
        if (tid < 128) {
            int r = tid >> 2, cq = tid & 3;
            As[(cq * 4 + 0) * 36 + r] = av.x; As[(cq * 4 + 1) * 36 + r] = av.y;
            As[(cq * 4 + 2) * 36 + r] = av.z; As[(cq * 4 + 3) * 36 + r] = av.w;
        }
        Bs[(kb + 0) * 136 + rb] = bv0.x; Bs[(kb + 1) * 136 + rb] = bv0.y;
        Bs[(kb + 2) * 136 + rb] = bv0.z; Bs[(kb + 3) * 136 + rb] = bv0.w;
        Bs[(kb + 4) * 136 + rb] = bv1.x; Bs[(kb + 5) * 136 + rb] = bv1.y;
        Bs[(kb + 6) * 136 + rb] = bv1.z; Bs[(kb + 7) * 136 + rb] = bv1.w;
        __syncthreads();
        #pragma unroll
        for (int kk = 0; kk < 16; ++kk) {
            float2 a2 = *(const float2*)&As[kk * 36 + tm * 2];
            float4 bv0_ = *(const float4*)&Bs[kk * 136 + tn * 8];
            float4 bv1_ = *(const float4*)&Bs[kk * 136 + tn * 8 + 4];
            float b_[8] = {bv0_.x, bv0_.y, bv0_.z, bv0_.w, bv1_.x, bv1_.y, bv1_.z, bv1_.w};
            #pragma unroll
            for (int j = 0; j < 8; ++j) {
                acc[0][j] = fmaf(a2.x, b_[j], acc[0][j]);
                acc[1][j] = fmaf(a2.y, b_[j], acc[1][j]);
            }
        }
    }
    float4 bb0 = *(const float4*)&b2g[tn * 8];
    float4 bb1 = *(const float4*)&b2g[tn * 8 + 4];
    #pragma unroll
    for (int i = 0; i < 2; ++i) {
        float* dst = &in2[(size_t)(m0 + tm * 2 + i) * 128 + tn * 8];
        *(float4*)dst       = make_float4(acc[i][0] + bb0.x, acc[i][1] + bb0.y,
                                          acc[i][2] + bb0.z, acc[i][3] + bb0.w);
        *(float4*)(dst + 4) = make_float4(acc[i][4] + bb1.x, acc[i][5] + bb1.y,
                                          acc[i][6] + bb1.z, acc[i][7] + bb1.w);
    }
}

// ---------------- lif2: 25-step m2 scan -> S2 ----------------
__global__ __launch_bounds__(256) void lif2_kernel(const float* __restrict__ in2,
                                                   const float* __restrict__ pb2,
                                                   float* __restrict__ S2) {
    const int i = blockIdx.x * 256 + threadIdx.x;    // 65536 = 512 b x 128 j
    const float be = fminf(fmaxf(pb2[0], 0.f), 1.f);
    float m = 0.f;
    #pragma unroll
    for (int t = 0; t < 25; ++t) {
        float r = (m > 1.f) ? 1.f : 0.f;
        m = fmaf(be, m, in2[(size_t)t * 65536 + i]) - r;
        S2[(size_t)t * 65536 + i] = (m > 1.f) ? 1.f : 0.f;
    }
}

// ---------------- fc3 + lif3 + out: one wave per batch row ----------------
__global__ __launch_bounds__(64) void fc3l_kernel(const float* __restrict__ S2,
                                                  const float* __restrict__ w3g,
                                                  const float* __restrict__ b3g,
                                                  const float* __restrict__ pb3,
                                                  float* __restrict__ out) {
    __shared__ float w3T[128 * 36];
    __shared__ float s2row[128];
    const int b = blockIdx.x;
    const int lane = threadIdx.x;
    for (int i = lane; i < 4480; i += 64) {
        int j = i >> 7, k = i & 127;
        w3T[k * 36 + j] = w3g[i];
    }
    const float be = fminf(fmaxf(pb3[0], 0.f), 1.f);
    const float bias = (lane < 35) ? b3g[lane] : 0.f;
    float m = 0.f;
    __syncthreads();
    for (int t = 0; t < 25; ++t) {
        float2 v = *(const float2*)&S2[(size_t)t * 65536 + b * 128 + lane * 2];
        *(float2*)&s2row[lane * 2] = v;
        __syncthreads();
        if (lane < 35) {
            float a = bias;
            #pragma unroll 8
            for (int k = 0; k < 128; ++k)
                a = fmaf(s2row[k], w3T[k * 36 + lane], a);
            float r = (m > 1.f) ? 1.f : 0.f;
            m = fmaf(be, m, a) - r;
            out[((size_t)t * 512 + b) * 35 + lane] = (m > 1.f) ? 1.f : 0.f;
        }
        __syncthreads();
    }
}

// ---------------- launch ----------------
extern "C" void kernel_launch(void* const* d_in, const int* in_sizes, int n_in,
                              void* d_out, int out_size, void* d_ws, size_t ws_size,
                              hipStream_t stream) {
    const float* x     = (const float*)d_in[0];
    const float* c1w   = (const float*)d_in[1];
    const float* c1b   = (const float*)d_in[2];
    const float* bn1g  = (const float*)d_in[3];
    const float* bn1b  = (const float*)d_in[4];
    const float* bn1m  = (const float*)d_in[5];
    const float* bn1v  = (const float*)d_in[6];
    const float* c2w   = (const float*)d_in[7];
    const float* c2b   = (const float*)d_in[8];
    const float* bn2g  = (const float*)d_in[9];
    const float* bn2b  = (const float*)d_in[10];
    const float* bn2m  = (const float*)d_in[11];
    const float* bn2v  = (const float*)d_in[12];
    const float* fc1w  = (const float*)d_in[13];
    const float* fc1b  = (const float*)d_in[14];
    const float* fc2w  = (const float*)d_in[15];
    const float* fc2b  = (const float*)d_in[16];
    const float* fc3w  = (const float*)d_in[17];
    const float* fc3b  = (const float*)d_in[18];
    const float* beta1 = (const float*)d_in[19];
    const float* beta2 = (const float*)d_in[20];
    const float* beta3 = (const float*)d_in[21];
    float* ws  = (float*)d_ws;
    float* out = (float*)d_out;

    // ATTRIBUTION PROBE: conv1 launched TWICE (idempotent — writes identical p1).
    // dur_us(this round) - 328 ≈ true cost of conv1.
    conv1_kernel<<<dim3(512, 5), 256, 0, stream>>>(x, c1w, c1b, bn1g, bn1b, bn1m, bn1v,
                                                   ws + WS_P1);
    conv1_kernel<<<dim3(512, 5), 256, 0, stream>>>(x, c1w, c1b, bn1g, bn1b, bn1m, bn1v,
                                                   ws + WS_P1);
    conv2_kernel<<<dim3(512, 5), 320, 0, stream>>>(ws + WS_P1, c2w, c2b, bn2g, bn2b, bn2m, bn2v,
                                                   ws + WS_FEAT);
    fc1_kernel<<<dim3(8, 2, 32), 256, 0, stream>>>(ws + WS_FEAT, fc1w, ws + WS_PART);
    lif1_kernel<<<512, 256, 0, stream>>>(ws + WS_PART, fc1b, beta1, ws + WS_S1);
    fc2g_kernel<<<400, 256, 0, stream>>>(ws + WS_S1, fc2w, fc2b, ws + WS_IN2);
    lif2_kernel<<<256, 256, 0, stream>>>(ws + WS_IN2, beta2, ws + WS_S2);
    fc3l_kernel<<<512, 64, 0, stream>>>(ws + WS_S2, fc3w, fc3b, beta3, out);
}

// Round 7
// 300.377 us; speedup vs baseline: 1.3609x; 1.3609x over previous
//
#include <hip/hip_runtime.h>

// ---------------- workspace layout (floats) ----------------
#define N_P1    (512*16*50*32)          // 13,107,200
#define N_FEAT  (512*12800)             // 6,553,600
#define N_PART  (32*512*256)            // 4,194,304

#define WS_P1    0
#define WS_FEAT  (WS_P1 + N_P1)
#define WS_PART  (WS_FEAT + N_FEAT)
// after conv2 consumes P1, its region is reused for the SNN tail (all < N_P1):
#define WS_S1    0                       // 25*512*256 = 3,276,800   [t][b][k]
#define WS_IN2   3276800                 // 25*512*128 = 1,638,400   [t][b][j]
#define WS_S2    4915200                 // 25*512*128 = 1,638,400   [t][b][j]
#define WS_IN3   6553600                 // 25*512*35  =   448,000   [t][b][c]

// ---------------- conv1: mean over T + conv3x3 + bn-fold + relu + pool ----------------
// grid (512, 5); 384 threads: one load item (352) / one compute item (320) per thread.
__global__ __launch_bounds__(384) void conv1_kernel(const float* __restrict__ x,
                                                    const float* __restrict__ w1,
                                                    const float* __restrict__ cb1,
                                                    const float* __restrict__ g1,
                                                    const float* __restrict__ bb1,
                                                    const float* __restrict__ m1g,
                                                    const float* __restrict__ v1,
                                                    float* __restrict__ p1) {
    __shared__ float xs[22 * 66];
    __shared__ float w1s[144];
    __shared__ float sh1s[16];
    const int b = blockIdx.x, s = blockIdx.y;
    const int tid = threadIdx.x;
    if (tid < 144) {
        int c = tid / 9;
        float inv = g1[c] * rsqrtf(v1[c] + 1e-5f);
        w1s[tid] = w1[tid] * inv;
    }
    if (tid >= 144 && tid < 160) {
        int c = tid - 144;
        float inv = g1[c] * rsqrtf(v1[c] + 1e-5f);
        sh1s[c] = cb1[c] * inv + bb1[c] - m1g[c] * inv;
    }
    if (tid >= 160 && tid < 204) {
        int q = tid - 160;
        xs[(q >> 1) * 66 + (q & 1) * 65] = 0.f;   // border cols
    }
    const int r0 = s * 20 - 1;
    const size_t TSTR = (size_t)512 * 6400;
    if (tid < 352) {
        int lr = tid >> 4, cq = tid & 15;
        int gr = r0 + lr;
        float4 a0 = make_float4(0.f, 0.f, 0.f, 0.f), a1 = a0, a2 = a0, a3 = a0;
        if (gr >= 0 && gr < 100) {
            const float* px = x + (size_t)b * 6400 + gr * 64 + cq * 4;
            #pragma unroll
            for (int tt = 0; tt < 24; tt += 4) {
                float4 v0 = *(const float4*)(px + (size_t)(tt + 0) * TSTR);
                float4 v1_ = *(const float4*)(px + (size_t)(tt + 1) * TSTR);
                float4 v2_ = *(const float4*)(px + (size_t)(tt + 2) * TSTR);
                float4 v3 = *(const float4*)(px + (size_t)(tt + 3) * TSTR);
                a0.x += v0.x; a0.y += v0.y; a0.z += v0.z; a0.w += v0.w;
                a1.x += v1_.x; a1.y += v1_.y; a1.z += v1_.z; a1.w += v1_.w;
                a2.x += v2_.x; a2.y += v2_.y; a2.z += v2_.z; a2.w += v2_.w;
                a3.x += v3.x; a3.y += v3.y; a3.z += v3.z; a3.w += v3.w;
            }
            float4 v = *(const float4*)(px + (size_t)24 * TSTR);
            a0.x += v.x; a0.y += v.y; a0.z += v.z; a0.w += v.w;
        }
        const float sc = 1.0f / 25.0f;
        float* d = &xs[lr * 66 + 1 + cq * 4];
        d[0] = (a0.x + a1.x + a2.x + a3.x) * sc;
        d[1] = (a0.y + a1.y + a2.y + a3.y) * sc;
        d[2] = (a0.z + a1.z + a2.z + a3.z) * sc;
        d[3] = (a0.w + a1.w + a2.w + a3.w) * sc;
    }
    __syncthreads();
    if (tid < 320) {
        int phl = tid >> 5, pw = tid & 31;
        int ph = s * 10 + phl;
        float win[4][4];
        #pragma unroll
        for (int a = 0; a < 4; ++a)
            #pragma unroll
            for (int c2 = 0; c2 < 4; ++c2)
                win[a][c2] = xs[(2 * phl + a) * 66 + 2 * pw + c2];
        #pragma unroll 1
        for (int c = 0; c < 16; ++c) {
            float s00 = 0.f, s01 = 0.f, s10 = 0.f, s11 = 0.f;
            #pragma unroll
            for (int dh = 0; dh < 3; ++dh)
                #pragma unroll
                for (int dw = 0; dw < 3; ++dw) {
                    float w = w1s[c * 9 + dh * 3 + dw];
                    s00 = fmaf(win[dh][dw],         w, s00);
                    s01 = fmaf(win[dh][dw + 1],     w, s01);
                    s10 = fmaf(win[dh + 1][dw],     w, s10);
                    s11 = fmaf(win[dh + 1][dw + 1], w, s11);
                }
            float m = fmaxf(fmaxf(s00, s01), fmaxf(s10, s11));
            float val = fmaxf(m + sh1s[c], 0.f);
            p1[(((size_t)b * 16 + c) * 50 + ph) * 32 + pw] = val;
        }
    }
}

// ---------------- conv2: conv3x3(16->32) + bn-fold + relu + pool (unchanged) ----------------
__global__ __launch_bounds__(320) void conv2_kernel(const float* __restrict__ p1,
                                                    const float* __restrict__ w2g,
                                                    const float* __restrict__ cb2,
                                                    const float* __restrict__ g2,
                                                    const float* __restrict__ bb2,
                                                    const float* __restrict__ m2g,
                                                    const float* __restrict__ v2,
                                                    float* __restrict__ feat) {
    __shared__ float ins[16 * 12 * 36];
    __shared__ float wl[16 * 9 * 32];
    __shared__ float sh2s[32];
    const int b = blockIdx.x, s = blockIdx.y;
    const int tid = threadIdx.x;
    const int chg = tid & 15, q = (tid >> 4) & 3, phl = tid >> 6;
    const int ph = s * 5 + phl;

    for (int i = tid; i < 192; i += 320) {
        int ci = i / 12, lr = i - ci * 12;
        int gr = s * 10 - 1 + lr;
        float* dst = &ins[(ci * 12 + lr) * 36];
        if (gr >= 0 && gr < 50) {
            const float* src = p1 + (((size_t)b * 16 + ci) * 50 + gr) * 32;
            float4 v0 = *(const float4*)src;
            dst[0] = 0.f; dst[1] = v0.x; dst[2] = v0.y; dst[3] = v0.z;
            #pragma unroll
            for (int qq = 1; qq < 8; ++qq) {
                float4 v = *(const float4*)(src + 4 * qq - 1);
                *(float4*)(dst + 4 * qq) = v;
            }
            dst[32] = src[31];
            dst[33] = 0.f; dst[34] = 0.f; dst[35] = 0.f;
        } else {
            #pragma unroll
            for (int qq = 0; qq < 9; ++qq) *(float4*)(dst + 4 * qq) = make_float4(0.f, 0.f, 0.f, 0.f);
        }
    }
    for (int i = tid; i < 4608; i += 320) {
        int c = i / 144, rem = i - c * 144;
        float inv = g2[c] * rsqrtf(v2[c] + 1e-5f);
        wl[rem * 32 + c] = w2g[i] * inv;
    }
    if (tid < 32) {
        float inv = g2[tid] * rsqrtf(v2[tid] + 1e-5f);
        sh2s[tid] = cb2[tid] * inv + bb2[tid] - m2g[tid] * inv;
    }
    __syncthreads();

    float acc[2][2][8];
    #pragma unroll
    for (int c = 0; c < 2; ++c)
        #pragma unroll
        for (int a = 0; a < 2; ++a)
            #pragma unroll
            for (int xx = 0; xx < 8; ++xx) acc[c][a][xx] = 0.f;
    const int xb = q * 8;
    #pragma unroll 1
    for (int ci = 0; ci < 16; ++ci) {
        float2 wv[9];
        #pragma unroll
        for (int t = 0; t < 9; ++t)
            wv[t] = *(const float2*)&wl[(ci * 9 + t) * 32 + 2 * chg];
        #pragma unroll
        for (int lr4 = 0; lr4 < 4; ++lr4) {
            const float* row = &ins[(ci * 12 + (2 * phl + lr4)) * 36 + xb];
            float v[10];
            float4 t0 = *(const float4*)&row[0];
            float4 t1 = *(const float4*)&row[4];
            float2 t2 = *(const float2*)&row[8];
            v[0]=t0.x; v[1]=t0.y; v[2]=t0.z; v[3]=t0.w;
            v[4]=t1.x; v[5]=t1.y; v[6]=t1.z; v[7]=t1.w;
            v[8]=t2.x; v[9]=t2.y;
            #pragma unroll
            for (int a = 0; a < 2; ++a) {
                const int dh = lr4 - a;
                if (dh >= 0 && dh <= 2) {
                    #pragma unroll
                    for (int dw = 0; dw < 3; ++dw) {
                        float w0 = wv[dh * 3 + dw].x;
                        float w1 = wv[dh * 3 + dw].y;
                        #pragma unroll
                        for (int xx = 0; xx < 8; ++xx) {
                            acc[0][a][xx] = fmaf(v[xx + dw], w0, acc[0][a][xx]);
                            acc[1][a][xx] = fmaf(v[xx + dw], w1, acc[1][a][xx]);
                        }
                    }
                }
            }
        }
    }
    #pragma unroll
    for (int ch = 0; ch < 2; ++ch) {
        const int c = 2 * chg + ch;
        const float sh = sh2s[c];
        #pragma unroll
        for (int p = 0; p < 4; ++p) {
            float m = fmaxf(fmaxf(acc[ch][0][2 * p], acc[ch][0][2 * p + 1]),
                            fmaxf(acc[ch][1][2 * p], acc[ch][1][2 * p + 1]));
            float val = fmaxf(m + sh, 0.f);
            feat[(((size_t)b * 32 + c) * 25 + ph) * 16 + q * 4 + p] = val;
        }
    }
}

// ---------------- fc1: split-K GEMM, 128x128 tile, 8x8 micro, register prefetch ----------------
// grid (4, 2, 32): K chunk 400 (25 kt of 16).
__global__ __launch_bounds__(256) void fc1_kernel(const float* __restrict__ feat,
                                                  const float* __restrict__ w,
                                                  float* __restrict__ part) {
    __shared__ float As[16 * 136];
    __shared__ float Bs[16 * 136];
    const int bx = blockIdx.x, by = blockIdx.y, bz = blockIdx.z;
    const int tid = threadIdx.x;
    const int tm = tid >> 4, tn = tid & 15;
    const int r = tid >> 2, cq = tid & 3;
    const int m0 = bx * 128, n0 = by * 128;
    const size_t aBase = (size_t)(m0 + r) * 12800 + bz * 400 + cq * 4;
    const size_t bBase = (size_t)(n0 + r) * 12800 + bz * 400 + cq * 4;
    float acc[8][8] = {};
    float4 a0 = *(const float4*)(feat + aBase);
    float4 a1 = *(const float4*)(feat + aBase + (size_t)64 * 12800);
    float4 b0 = *(const float4*)(w    + bBase);
    float4 b1 = *(const float4*)(w    + bBase + (size_t)64 * 12800);

    for (int kt = 0; kt < 25; ++kt) {
        __syncthreads();
        As[(cq * 4 + 0) * 136 + r]      = a0.x; As[(cq * 4 + 1) * 136 + r]      = a0.y;
        As[(cq * 4 + 2) * 136 + r]      = a0.z; As[(cq * 4 + 3) * 136 + r]      = a0.w;
        As[(cq * 4 + 0) * 136 + 64 + r] = a1.x; As[(cq * 4 + 1) * 136 + 64 + r] = a1.y;
        As[(cq * 4 + 2) * 136 + 64 + r] = a1.z; As[(cq * 4 + 3) * 136 + 64 + r] = a1.w;
        Bs[(cq * 4 + 0) * 136 + r]      = b0.x; Bs[(cq * 4 + 1) * 136 + r]      = b0.y;
        Bs[(cq * 4 + 2) * 136 + r]      = b0.z; Bs[(cq * 4 + 3) * 136 + r]      = b0.w;
        Bs[(cq * 4 + 0) * 136 + 64 + r] = b1.x; Bs[(cq * 4 + 1) * 136 + 64 + r] = b1.y;
        Bs[(cq * 4 + 2) * 136 + 64 + r] = b1.z; Bs[(cq * 4 + 3) * 136 + 64 + r] = b1.w;
        __syncthreads();
        if (kt < 24) {                       // prefetch kt+1 (overlaps with compute)
            const int o = (kt + 1) * 16;
            a0 = *(const float4*)(feat + aBase + o);
            a1 = *(const float4*)(feat + aBase + (size_t)64 * 12800 + o);
            b0 = *(const float4*)(w    + bBase + o);
            b1 = *(const float4*)(w    + bBase + (size_t)64 * 12800 + o);
        }
        #pragma unroll
        for (int kk = 0; kk < 16; ++kk) {
            float4 av0 = *(const float4*)&As[kk * 136 + tm * 8];
            float4 av1 = *(const float4*)&As[kk * 136 + tm * 8 + 4];
            float4 bv0 = *(const float4*)&Bs[kk * 136 + tn * 8];
            float4 bv1 = *(const float4*)&Bs[kk * 136 + tn * 8 + 4];
            float a_[8] = {av0.x, av0.y, av0.z, av0.w, av1.x, av1.y, av1.z, av1.w};
            float b_[8] = {bv0.x, bv0.y, bv0.z, bv0.w, bv1.x, bv1.y, bv1.z, bv1.w};
            #pragma unroll
            for (int i = 0; i < 8; ++i)
                #pragma unroll
                for (int j = 0; j < 8; ++j)
                    acc[i][j] = fmaf(a_[i], b_[j], acc[i][j]);
        }
    }
    #pragma unroll
    for (int i = 0; i < 8; ++i) {
        float* dst = &part[(size_t)bz * 131072 + (size_t)(m0 + tm * 8 + i) * 256 + n0 + tn * 8];
        *(float4*)dst       = make_float4(acc[i][0], acc[i][1], acc[i][2], acc[i][3]);
        *(float4*)(dst + 4) = make_float4(acc[i][4], acc[i][5], acc[i][6], acc[i][7]);
    }
}

// ---------------- lif1: reduce fc1 partials + 25-step m1 scan -> S1 [t][b][k] ----------------
__global__ __launch_bounds__(256) void lif1_kernel(const float* __restrict__ part,
                                                   const float* __restrict__ b1g,
                                                   const float* __restrict__ pb1,
                                                   float* __restrict__ S1) {
    const int i = blockIdx.x * 256 + threadIdx.x;    // 131072 = 512 b x 256 k
    const int k = i & 255;
    float cu = b1g[k];
    #pragma unroll 8
    for (int z = 0; z < 32; ++z) cu += part[(size_t)z * 131072 + i];
    const float be = fminf(fmaxf(pb1[0], 0.f), 1.f);
    float m = 0.f;
    #pragma unroll
    for (int t = 0; t < 25; ++t) {
        float r = (m > 1.f) ? 1.f : 0.f;
        m = fmaf(be, m, cu) - r;
        S1[(size_t)t * 131072 + i] = (m > 1.f) ? 1.f : 0.f;
    }
}

// ---------------- fc2 GEMM: in2(12800,128) = S1 @ w2^T + b2, with prefetch ----------------
__global__ __launch_bounds__(256) void fc2g_kernel(const float* __restrict__ S1,
                                                   const float* __restrict__ w2g,
                                                   const float* __restrict__ b2g,
                                                   float* __restrict__ in2) {
    __shared__ float As[16 * 36];
    __shared__ float Bs[16 * 136];
    const int m0 = blockIdx.x * 32;
    const int tid = threadIdx.x;
    const int tm = tid >> 4, tn = tid & 15;
    const int ra = tid >> 2, cqa = tid & 3;
    const int rb = tid >> 1, kb = (tid & 1) * 8;
    float acc[2][8] = {};
    float4 av = make_float4(0.f, 0.f, 0.f, 0.f);
    if (tid < 128) av = *(const float4*)&S1[(size_t)(m0 + ra) * 256 + cqa * 4];
    float4 bv0 = *(const float4*)&w2g[rb * 256 + kb];
    float4 bv1 = *(const float4*)&w2g[rb * 256 + kb + 4];

    for (int kt = 0; kt < 16; ++kt) {
        __syncthreads();
        if (tid < 128) {
            As[(cqa * 4 + 0) * 36 + ra] = av.x; As[(cqa * 4 + 1) * 36 + ra] = av.y;
            As[(cqa * 4 + 2) * 36 + ra] = av.z; As[(cqa * 4 + 3) * 36 + ra] = av.w;
        }
        Bs[(kb + 0) * 136 + rb] = bv0.x; Bs[(kb + 1) * 136 + rb] = bv0.y;
        Bs[(kb + 2) * 136 + rb] = bv0.z; Bs[(kb + 3) * 136 + rb] = bv0.w;
        Bs[(kb + 4) * 136 + rb] = bv1.x; Bs[(kb + 5) * 136 + rb] = bv1.y;
        Bs[(kb + 6) * 136 + rb] = bv1.z; Bs[(kb + 7) * 136 + rb] = bv1.w;
        __syncthreads();
        if (kt < 15) {                        // prefetch kt+1
            const int o = (kt + 1) * 16;
            if (tid < 128) av = *(const float4*)&S1[(size_t)(m0 + ra) * 256 + o + cqa * 4];
            bv0 = *(const float4*)&w2g[rb * 256 + o + kb];
            bv1 = *(const float4*)&w2g[rb * 256 + o + kb + 4];
        }
        #pragma unroll
        for (int kk = 0; kk < 16; ++kk) {
            float2 a2 = *(const float2*)&As[kk * 36 + tm * 2];
            float4 bw0 = *(const float4*)&Bs[kk * 136 + tn * 8];
            float4 bw1 = *(const float4*)&Bs[kk * 136 + tn * 8 + 4];
            float b_[8] = {bw0.x, bw0.y, bw0.z, bw0.w, bw1.x, bw1.y, bw1.z, bw1.w};
            #pragma unroll
            for (int j = 0; j < 8; ++j) {
                acc[0][j] = fmaf(a2.x, b_[j], acc[0][j]);
                acc[1][j] = fmaf(a2.y, b_[j], acc[1][j]);
            }
        }
    }
    float4 bb0 = *(const float4*)&b2g[tn * 8];
    float4 bb1 = *(const float4*)&b2g[tn * 8 + 4];
    #pragma unroll
    for (int i = 0; i < 2; ++i) {
        float* dst = &in2[(size_t)(m0 + tm * 2 + i) * 128 + tn * 8];
        *(float4*)dst       = make_float4(acc[i][0] + bb0.x, acc[i][1] + bb0.y,
                                          acc[i][2] + bb0.z, acc[i][3] + bb0.w);
        *(float4*)(dst + 4) = make_float4(acc[i][4] + bb1.x, acc[i][5] + bb1.y,
                                          acc[i][6] + bb1.z, acc[i][7] + bb1.w);
    }
}

// ---------------- lif2: 25-step m2 scan -> S2 ----------------
__global__ __launch_bounds__(256) void lif2_kernel(const float* __restrict__ in2,
                                                   const float* __restrict__ pb2,
                                                   float* __restrict__ S2) {
    const int i = blockIdx.x * 256 + threadIdx.x;    // 65536
    const float be = fminf(fmaxf(pb2[0], 0.f), 1.f);
    float m = 0.f;
    #pragma unroll
    for (int t = 0; t < 25; ++t) {
        float r = (m > 1.f) ? 1.f : 0.f;
        m = fmaf(be, m, in2[(size_t)t * 65536 + i]) - r;
        S2[(size_t)t * 65536 + i] = (m > 1.f) ? 1.f : 0.f;
    }
}

// ---------------- fc3 GEMM: in3(12800,35) = S2(12800,128) @ w3^T + b3 ----------------
// grid 400, block 256: BM=32, micro 2 rows x 3 cols (tn, tn+16, tn+32 if <35).
__global__ __launch_bounds__(256) void fc3g_kernel(const float* __restrict__ S2,
                                                   const float* __restrict__ w3g,
                                                   const float* __restrict__ b3g,
                                                   float* __restrict__ in3) {
    __shared__ float As[16 * 36];   // [kk][r]
    __shared__ float Bs[16 * 48];   // [kk][c]  (stride 48 so tn+32 stays in-bounds)
    const int m0 = blockIdx.x * 32;
    const int tid = threadIdx.x;
    const int tm = tid >> 4, tn = tid & 15;
    float acc[2][3] = {};
    for (int kt = 0; kt < 8; ++kt) {
        __syncthreads();
        if (tid < 128) {
            int r = tid >> 2, cq = tid & 3;
            float4 av = *(const float4*)&S2[(size_t)(m0 + r) * 128 + kt * 16 + cq * 4];
            As[(cq * 4 + 0) * 36 + r] = av.x; As[(cq * 4 + 1) * 36 + r] = av.y;
            As[(cq * 4 + 2) * 36 + r] = av.z; As[(cq * 4 + 3) * 36 + r] = av.w;
        }
        for (int i = tid; i < 560; i += 256) {
            int kk = i / 35, c = i - kk * 35;
            Bs[kk * 48 + c] = w3g[c * 128 + kt * 16 + kk];
        }
        __syncthreads();
        #pragma unroll
        for (int kk = 0; kk < 16; ++kk) {
            float2 a2 = *(const float2*)&As[kk * 36 + tm * 2];
            float w0 = Bs[kk * 48 + tn];
            float w1 = Bs[kk * 48 + tn + 16];
            float w2 = Bs[kk * 48 + tn + 32];
            acc[0][0] = fmaf(a2.x, w0, acc[0][0]); acc[1][0] = fmaf(a2.y, w0, acc[1][0]);
            acc[0][1] = fmaf(a2.x, w1, acc[0][1]); acc[1][1] = fmaf(a2.y, w1, acc[1][1]);
            acc[0][2] = fmaf(a2.x, w2, acc[0][2]); acc[1][2] = fmaf(a2.y, w2, acc[1][2]);
        }
    }
    const float bias0 = b3g[tn];
    const float bias1 = b3g[tn + 16];
    const float bias2 = (tn < 3) ? b3g[tn + 32] : 0.f;
    #pragma unroll
    for (int i = 0; i < 2; ++i) {
        const size_t row = (size_t)(m0 + tm * 2 + i) * 35;
        in3[row + tn]      = acc[i][0] + bias0;
        in3[row + tn + 16] = acc[i][1] + bias1;
        if (tn < 3) in3[row + tn + 32] = acc[i][2] + bias2;
    }
}

// ---------------- lif3: 25-step m3 scan -> out (coalesced [t][b][c]) ----------------
__global__ __launch_bounds__(256) void lif3_kernel(const float* __restrict__ in3,
                                                   const float* __restrict__ pb3,
                                                   float* __restrict__ out) {
    const int i = blockIdx.x * 256 + threadIdx.x;    // 17920 = 512 b x 35 c
    if (i >= 17920) return;
    const float be = fminf(fmaxf(pb3[0], 0.f), 1.f);
    float m = 0.f;
    #pragma unroll
    for (int t = 0; t < 25; ++t) {
        float r = (m > 1.f) ? 1.f : 0.f;
        m = fmaf(be, m, in3[(size_t)t * 17920 + i]) - r;
        out[(size_t)t * 17920 + i] = (m > 1.f) ? 1.f : 0.f;
    }
}

// ---------------- launch ----------------
extern "C" void kernel_launch(void* const* d_in, const int* in_sizes, int n_in,
                              void* d_out, int out_size, void* d_ws, size_t ws_size,
                              hipStream_t stream) {
    const float* x     = (const float*)d_in[0];
    const float* c1w   = (const float*)d_in[1];
    const float* c1b   = (const float*)d_in[2];
    const float* bn1g  = (const float*)d_in[3];
    const float* bn1b  = (const float*)d_in[4];
    const float* bn1m  = (const float*)d_in[5];
    const float* bn1v  = (const float*)d_in[6];
    const float* c2w   = (const float*)d_in[7];
    const float* c2b   = (const float*)d_in[8];
    const float* bn2g  = (const float*)d_in[9];
    const float* bn2b  = (const float*)d_in[10];
    const float* bn2m  = (const float*)d_in[11];
    const float* bn2v  = (const float*)d_in[12];
    const float* fc1w  = (const float*)d_in[13];
    const float* fc1b  = (const float*)d_in[14];
    const float* fc2w  = (const float*)d_in[15];
    const float* fc2b  = (const float*)d_in[16];
    const float* fc3w  = (const float*)d_in[17];
    const float* fc3b  = (const float*)d_in[18];
    const float* beta1 = (const float*)d_in[19];
    const float* beta2 = (const float*)d_in[20];
    const float* beta3 = (const float*)d_in[21];
    float* ws  = (float*)d_ws;
    float* out = (float*)d_out;

    conv1_kernel<<<dim3(512, 5), 384, 0, stream>>>(x, c1w, c1b, bn1g, bn1b, bn1m, bn1v,
                                                   ws + WS_P1);
    conv2_kernel<<<dim3(512, 5), 320, 0, stream>>>(ws + WS_P1, c2w, c2b, bn2g, bn2b, bn2m, bn2v,
                                                   ws + WS_FEAT);
    fc1_kernel<<<dim3(4, 2, 32), 256, 0, stream>>>(ws + WS_FEAT, fc1w, ws + WS_PART);
    lif1_kernel<<<512, 256, 0, stream>>>(ws + WS_PART, fc1b, beta1, ws + WS_S1);
    fc2g_kernel<<<400, 256, 0, stream>>>(ws + WS_S1, fc2w, fc2b, ws + WS_IN2);
    lif2_kernel<<<256, 256, 0, stream>>>(ws + WS_IN2, beta2, ws + WS_S2);
    fc3g_kernel<<<400, 256, 0, stream>>>(ws + WS_S2, fc3w, fc3b, ws + WS_IN3);
    lif3_kernel<<<70, 256, 0, stream>>>(ws + WS_IN3, beta3, out);
}